// Round 12
// baseline (1141.579 us; speedup 1.0000x reference)
//
#include <hip/hip_runtime.h>
#include <hip/hip_fp16.h>
#include <math.h>

#define KF 8
#define LL 8
#define TT (1 << 18)
#define FF 2
#define HID 64
#define INF 16          // L*F = MLP input dim
// Legacy strides for the unbucketed fallback kernels:
#define W1S 1056
#define BS  68

#define NENT (KF * LL * TT)           // 16,777,216 table entries
#define TAB_BYTES ((size_t)NENT * 4)  // half2 table: 64 MiB

// ---------------------------------------------------------------------------
// Round-12: r10/r11 (inline-asm 64-burst) both crashed — technique abandoned
// after two failures. Revert to r8's verified structure and apply the one
// PROVEN-SAFE ILP lever: r3's pure-C++ two-point interleave (it held 16
// loads in flight at VGPR 68, no asm). In r3 it was neutral only because
// 38.4KB LDS + VGPR 68 halved occupancy; the bucketed kernel's LDS is 5KB,
// so VGPR ~80-110 keeps 16 waves/CU -> outstanding/CU ~84 -> ~256.
// Per level: issue A's 8 gathers -> issue B's 8 -> consume A (B in flight)
// -> consume B. Both points share cluster k -> same table base + weights.
// Decision rule (pre-committed): VGPR>=80 & flat 135us => per-CU L2/TA
// request-service wall => declare roofline.
// ---------------------------------------------------------------------------

__global__ __launch_bounds__(256) void repack_tables_fp16(
    const float4* __restrict__ src, uint4* __restrict__ dst, int nthreads)
{
    const int gid = blockIdx.x * blockDim.x + threadIdx.x;
    if (gid >= nthreads) return;
    const size_t b = (size_t)gid * 4;            // float4 index (2 entries each)

    const float4 f0 = src[b + 0];
    const float4 f1 = src[b + 1];
    const float4 f2 = src[b + 2];
    const float4 f3 = src[b + 3];

    uint4 d0, d1;
    {
        __half2 h;
        h = __floats2half2_rn(f0.x, f0.y); d0.x = *reinterpret_cast<unsigned*>(&h);
        h = __floats2half2_rn(f0.z, f0.w); d0.y = *reinterpret_cast<unsigned*>(&h);
        h = __floats2half2_rn(f1.x, f1.y); d0.z = *reinterpret_cast<unsigned*>(&h);
        h = __floats2half2_rn(f1.z, f1.w); d0.w = *reinterpret_cast<unsigned*>(&h);
        h = __floats2half2_rn(f2.x, f2.y); d1.x = *reinterpret_cast<unsigned*>(&h);
        h = __floats2half2_rn(f2.z, f2.w); d1.y = *reinterpret_cast<unsigned*>(&h);
        h = __floats2half2_rn(f3.x, f3.y); d1.z = *reinterpret_cast<unsigned*>(&h);
        h = __floats2half2_rn(f3.z, f3.w); d1.w = *reinterpret_cast<unsigned*>(&h);
    }
    dst[(size_t)gid * 2 + 0] = d0;
    dst[(size_t)gid * 2 + 1] = d1;
}

__global__ void zero_cursors(unsigned* __restrict__ cursors)
{
    if (threadIdx.x < KF) cursors[threadIdx.x] = 0u;
}

// Phase 1: per-point argmin assignment + bucket scatter.
__global__ __launch_bounds__(256) void bucket_points(
    const float* __restrict__ positions,
    const float* __restrict__ centroids,
    unsigned* __restrict__ cursors,      // [KF] running cursors (pre-zeroed)
    unsigned* __restrict__ indices,      // [KF * npts] bucket storage
    int npts)
{
    __shared__ float sC[KF * 3];
    __shared__ unsigned lcnt[KF];
    __shared__ unsigned lbase[KF];

    const int tid = threadIdx.x;
    if (tid < KF * 3) sC[tid] = centroids[tid];
    if (tid < KF) lcnt[tid] = 0u;
    __syncthreads();

    const int gid = blockIdx.x * blockDim.x + tid;
    int assign = 0;
    unsigned lrank = 0;
    const bool valid = (gid < npts);
    if (valid) {
        const float px = positions[gid * 3 + 0];
        const float py = positions[gid * 3 + 1];
        const float pz = positions[gid * 3 + 2];
        float best = 1e30f;
        #pragma unroll
        for (int k = 0; k < KF; ++k) {
            float dx = px - sC[k * 3 + 0];
            float dy = py - sC[k * 3 + 1];
            float dz = pz - sC[k * 3 + 2];
            float d2 = fmaf(dx, dx, fmaf(dy, dy, dz * dz));
            bool lt = d2 < best;
            assign = lt ? k : assign;
            best = lt ? d2 : best;
        }
        lrank = atomicAdd(&lcnt[assign], 1u);
    }
    __syncthreads();
    if (tid < KF) lbase[tid] = atomicAdd(&cursors[tid], lcnt[tid]);
    __syncthreads();
    if (valid)
        indices[(size_t)assign * npts + lbase[assign] + lrank] = (unsigned)gid;
}

// Phase 2: balanced chunked-XCD density kernel, TWO points per thread.
// Each block covers 512 bucket ranks; thread t takes base+t and base+t+256.
__global__ __launch_bounds__(256) void propnet_density_balanced(
    const float* __restrict__ positions,
    const __half2* __restrict__ tables,       // repacked half2 table (ws)
    const float* __restrict__ W1,
    const float* __restrict__ b1,
    const float* __restrict__ W2,
    const float* __restrict__ b2,
    const unsigned* __restrict__ cursors,     // final per-cluster counts
    const unsigned* __restrict__ indices,     // [KF * npts]
    float* __restrict__ out,
    int npts, int cpx)
{
    __shared__ float sW1[INF * HID];          // 4096 B, single cluster
    __shared__ float sB1[HID];
    __shared__ float sW2[HID];
    __shared__ unsigned snk[KF];

    const int tid = threadIdx.x;
    const int b = blockIdx.x;
    const int v = (b & 7) * cpx + (b >> 3);   // chunked XCD swizzle

    if (tid < KF) snk[tid] = cursors[tid];
    __syncthreads();

    // Locate (cluster k, slot) for virtual block v; blocks are 512 ranks.
    int k = -1;
    unsigned slot = 0, nk = 0, acc = 0;
    #pragma unroll
    for (int kk = 0; kk < KF; ++kk) {
        const unsigned n = snk[kk];
        const unsigned nbk = (n + 511u) >> 9;        // 512-pt blocks for kk
        if (k < 0 && (unsigned)v < acc + nbk) {
            k = kk; slot = (unsigned)v - acc; nk = n;
        }
        acc += nbk;
    }
    if (k < 0) return;                               // v beyond vtotal (few)

    // Single-cluster weight staging (coalesced; wave-uniform reads later).
    for (int idx = tid; idx < INF * HID; idx += blockDim.x)
        sW1[idx] = W1[k * (INF * HID) + idx];
    if (tid < HID) {
        sB1[tid] = b1[k * HID + tid];
        sW2[tid] = W2[k * HID + tid];
    }
    __syncthreads();

    const unsigned base = slot * 512u;
    if (base >= nk) return;                          // safety (locate covers)
    const unsigned rA = base + (unsigned)tid;
    const unsigned rB = rA + 256u;
    const bool vA = rA < nk;
    const bool vB = rB < nk;
    const unsigned last = nk - 1u;
    const unsigned iA = indices[(size_t)k * npts + (vA ? rA : last)];
    const unsigned iB = indices[(size_t)k * npts + (vB ? rB : last)];

    const float pxA = positions[iA * 3 + 0];
    const float pyA = positions[iA * 3 + 1];
    const float pzA = positions[iA * 3 + 2];
    const float pxB = positions[iB * 3 + 0];
    const float pyB = positions[iB * 3 + 1];
    const float pzB = positions[iB * 3 + 2];

    // ---- hash encode, both points fused per level (16 loads in flight) ----
    float encA[INF], encB[INF];
    const __half2* __restrict__ tab = tables + (size_t)k * (LL * (size_t)TT);

    #pragma unroll
    for (int l = 0; l < LL; ++l) {
        const float res = (float)(16 << l);
        const unsigned M = TT - 1;
        const __half2* __restrict__ tl = tab + (size_t)l * TT;

        // --- point A: hashes + issue 8 gathers ---
        const float sxA = pxA * res, syA = pyA * res, szA = pzA * res;
        const float fxA = floorf(sxA), fyA = floorf(syA), fzA = floorf(szA);
        const float wxA = sxA - fxA, wyA = syA - fyA, wzA = szA - fzA;
        const unsigned ixA = (unsigned)(int)fxA;
        const unsigned iyA = (unsigned)(int)fyA;
        const unsigned izA = (unsigned)(int)fzA;
        const unsigned ax0 = ixA, ax1 = ixA + 1u;
        const unsigned ay0 = iyA * 2654435761u, ay1 = (iyA + 1u) * 2654435761u;
        const unsigned az0 = izA * 805459861u,  az1 = (izA + 1u) * 805459861u;

        const __half2 a000 = tl[(ax0 ^ ay0 ^ az0) & M];
        const __half2 a001 = tl[(ax0 ^ ay0 ^ az1) & M];
        const __half2 a010 = tl[(ax0 ^ ay1 ^ az0) & M];
        const __half2 a011 = tl[(ax0 ^ ay1 ^ az1) & M];
        const __half2 a100 = tl[(ax1 ^ ay0 ^ az0) & M];
        const __half2 a101 = tl[(ax1 ^ ay0 ^ az1) & M];
        const __half2 a110 = tl[(ax1 ^ ay1 ^ az0) & M];
        const __half2 a111 = tl[(ax1 ^ ay1 ^ az1) & M];

        // --- point B: hashes + issue 8 gathers (in flight over A's FMAs) ---
        const float sxB = pxB * res, syB = pyB * res, szB = pzB * res;
        const float fxB = floorf(sxB), fyB = floorf(syB), fzB = floorf(szB);
        const float wxB = sxB - fxB, wyB = syB - fyB, wzB = szB - fzB;
        const unsigned ixB = (unsigned)(int)fxB;
        const unsigned iyB = (unsigned)(int)fyB;
        const unsigned izB = (unsigned)(int)fzB;
        const unsigned bx0 = ixB, bx1 = ixB + 1u;
        const unsigned by0 = iyB * 2654435761u, by1 = (iyB + 1u) * 2654435761u;
        const unsigned bz0 = izB * 805459861u,  bz1 = (izB + 1u) * 805459861u;

        const __half2 b000 = tl[(bx0 ^ by0 ^ bz0) & M];
        const __half2 b001 = tl[(bx0 ^ by0 ^ bz1) & M];
        const __half2 b010 = tl[(bx0 ^ by1 ^ bz0) & M];
        const __half2 b011 = tl[(bx0 ^ by1 ^ bz1) & M];
        const __half2 b100 = tl[(bx1 ^ by0 ^ bz0) & M];
        const __half2 b101 = tl[(bx1 ^ by0 ^ bz1) & M];
        const __half2 b110 = tl[(bx1 ^ by1 ^ bz0) & M];
        const __half2 b111 = tl[(bx1 ^ by1 ^ bz1) & M];

        // --- consume A (waits vmcnt(8); B still outstanding) ---
        {
            const float ux = 1.f - wxA, uy = 1.f - wyA, uz = 1.f - wzA;
            const float w000 = ux * uy * uz, w001 = ux * uy * wzA;
            const float w010 = ux * wyA * uz, w011 = ux * wyA * wzA;
            const float w100 = wxA * uy * uz, w101 = wxA * uy * wzA;
            const float w110 = wxA * wyA * uz, w111 = wxA * wyA * wzA;
            encA[l * 2 + 0] = __low2float(a000) * w000 + __low2float(a001) * w001
                            + __low2float(a010) * w010 + __low2float(a011) * w011
                            + __low2float(a100) * w100 + __low2float(a101) * w101
                            + __low2float(a110) * w110 + __low2float(a111) * w111;
            encA[l * 2 + 1] = __high2float(a000) * w000 + __high2float(a001) * w001
                            + __high2float(a010) * w010 + __high2float(a011) * w011
                            + __high2float(a100) * w100 + __high2float(a101) * w101
                            + __high2float(a110) * w110 + __high2float(a111) * w111;
        }
        // --- consume B ---
        {
            const float ux = 1.f - wxB, uy = 1.f - wyB, uz = 1.f - wzB;
            const float w000 = ux * uy * uz, w001 = ux * uy * wzB;
            const float w010 = ux * wyB * uz, w011 = ux * wyB * wzB;
            const float w100 = wxB * uy * uz, w101 = wxB * uy * wzB;
            const float w110 = wxB * wyB * uz, w111 = wxB * wyB * wzB;
            encB[l * 2 + 0] = __low2float(b000) * w000 + __low2float(b001) * w001
                            + __low2float(b010) * w010 + __low2float(b011) * w011
                            + __low2float(b100) * w100 + __low2float(b101) * w101
                            + __low2float(b110) * w110 + __low2float(b111) * w111;
            encB[l * 2 + 1] = __high2float(b000) * w000 + __high2float(b001) * w001
                            + __high2float(b010) * w010 + __high2float(b011) * w011
                            + __high2float(b100) * w100 + __high2float(b101) * w101
                            + __high2float(b110) * w110 + __high2float(b111) * w111;
        }
    }

    // ---- MLP for both points (wave-uniform LDS broadcasts) ----
    const float4* __restrict__ w1k = (const float4*)sW1;
    const float4* __restrict__ b1k = (const float4*)sB1;
    const float4* __restrict__ w2k = (const float4*)sW2;

    const float bias2 = b2[k];
    float outvA = bias2;
    float outvB = bias2;
    #pragma unroll
    for (int j4 = 0; j4 < HID / 4; ++j4) {
        float4 aA = b1k[j4];
        float4 aB = aA;
        #pragma unroll
        for (int i = 0; i < INF; ++i) {
            const float4 w = w1k[i * (HID / 4) + j4];
            const float eA = encA[i];
            const float eB = encB[i];
            aA.x = fmaf(eA, w.x, aA.x);
            aA.y = fmaf(eA, w.y, aA.y);
            aA.z = fmaf(eA, w.z, aA.z);
            aA.w = fmaf(eA, w.w, aA.w);
            aB.x = fmaf(eB, w.x, aB.x);
            aB.y = fmaf(eB, w.y, aB.y);
            aB.z = fmaf(eB, w.z, aB.z);
            aB.w = fmaf(eB, w.w, aB.w);
        }
        aA.x = fmaxf(aA.x, 0.f); aA.y = fmaxf(aA.y, 0.f);
        aA.z = fmaxf(aA.z, 0.f); aA.w = fmaxf(aA.w, 0.f);
        aB.x = fmaxf(aB.x, 0.f); aB.y = fmaxf(aB.y, 0.f);
        aB.z = fmaxf(aB.z, 0.f); aB.w = fmaxf(aB.w, 0.f);
        const float4 w2v = w2k[j4];
        outvA = fmaf(aA.x, w2v.x, outvA);
        outvA = fmaf(aA.y, w2v.y, outvA);
        outvA = fmaf(aA.z, w2v.z, outvA);
        outvA = fmaf(aA.w, w2v.w, outvA);
        outvB = fmaf(aB.x, w2v.x, outvB);
        outvB = fmaf(aB.y, w2v.y, outvB);
        outvB = fmaf(aB.z, w2v.z, outvB);
        outvB = fmaf(aB.w, w2v.w, outvB);
    }

    if (vA) out[iA] = expf(outvA);
    if (vB) out[iB] = expf(outvB);
}

// ---------------- Fallback tier 1: unbucketed fp16 (round-5/6 kernel) -------
__global__ __launch_bounds__(256) void propnet_density_kernel_h(
    const float* __restrict__ positions,
    const float* __restrict__ centroids,
    const __half2* __restrict__ tables,
    const float* __restrict__ W1,
    const float* __restrict__ b1,
    const float* __restrict__ W2,
    const float* __restrict__ b2,
    float* __restrict__ out,
    int npts)
{
    __shared__ float sW1[KF * W1S];
    __shared__ float sB1[KF * BS];
    __shared__ float sW2[KF * BS];
    __shared__ float sB2[KF];
    __shared__ float sC[KF * 3];

    const int tid = threadIdx.x;

    for (int idx = tid; idx < KF * INF * HID; idx += blockDim.x) {
        int k = idx >> 10;
        int r = idx & 1023;
        sW1[k * W1S + r] = W1[idx];
    }
    for (int idx = tid; idx < KF * HID; idx += blockDim.x) {
        int k = idx >> 6;
        int r = idx & 63;
        sB1[k * BS + r] = b1[idx];
        sW2[k * BS + r] = W2[idx];
    }
    if (tid < KF) sB2[tid] = b2[tid];
    if (tid < KF * 3) sC[tid] = centroids[tid];
    __syncthreads();

    const int gid = blockIdx.x * blockDim.x + tid;
    if (gid >= npts) return;

    const float px = positions[gid * 3 + 0];
    const float py = positions[gid * 3 + 1];
    const float pz = positions[gid * 3 + 2];

    int assign = 0;
    float best = 1e30f;
    #pragma unroll
    for (int k = 0; k < KF; ++k) {
        float dx = px - sC[k * 3 + 0];
        float dy = py - sC[k * 3 + 1];
        float dz = pz - sC[k * 3 + 2];
        float d2 = fmaf(dx, dx, fmaf(dy, dy, dz * dz));
        bool lt = d2 < best;
        assign = lt ? k : assign;
        best = lt ? d2 : best;
    }

    float enc[INF];
    const __half2* __restrict__ tab =
        tables + (size_t)assign * (LL * (size_t)TT);

    #pragma unroll
    for (int l = 0; l < LL; ++l) {
        const float res = (float)(16 << l);
        const float sx = px * res, sy = py * res, sz = pz * res;
        const float fx = floorf(sx), fy = floorf(sy), fz = floorf(sz);
        const float wx = sx - fx, wy = sy - fy, wz = sz - fz;
        const unsigned ix = (unsigned)(int)fx;
        const unsigned iy = (unsigned)(int)fy;
        const unsigned iz = (unsigned)(int)fz;

        const __half2* __restrict__ tl = tab + (size_t)l * TT;

        const unsigned hx0 = ix;
        const unsigned hx1 = ix + 1u;
        const unsigned hy0 = iy * 2654435761u;
        const unsigned hy1 = (iy + 1u) * 2654435761u;
        const unsigned hz0 = iz * 805459861u;
        const unsigned hz1 = (iz + 1u) * 805459861u;
        const unsigned M = TT - 1;

        const __half2 c000 = tl[(hx0 ^ hy0 ^ hz0) & M];
        const __half2 c001 = tl[(hx0 ^ hy0 ^ hz1) & M];
        const __half2 c010 = tl[(hx0 ^ hy1 ^ hz0) & M];
        const __half2 c011 = tl[(hx0 ^ hy1 ^ hz1) & M];
        const __half2 c100 = tl[(hx1 ^ hy0 ^ hz0) & M];
        const __half2 c101 = tl[(hx1 ^ hy0 ^ hz1) & M];
        const __half2 c110 = tl[(hx1 ^ hy1 ^ hz0) & M];
        const __half2 c111 = tl[(hx1 ^ hy1 ^ hz1) & M];

        const float ux = 1.f - wx, uy = 1.f - wy, uz = 1.f - wz;
        const float w000 = ux * uy * uz, w001 = ux * uy * wz;
        const float w010 = ux * wy * uz, w011 = ux * wy * wz;
        const float w100 = wx * uy * uz, w101 = wx * uy * wz;
        const float w110 = wx * wy * uz, w111 = wx * wy * wz;

        enc[l * 2 + 0] = __low2float(c000) * w000 + __low2float(c001) * w001
                       + __low2float(c010) * w010 + __low2float(c011) * w011
                       + __low2float(c100) * w100 + __low2float(c101) * w101
                       + __low2float(c110) * w110 + __low2float(c111) * w111;
        enc[l * 2 + 1] = __high2float(c000) * w000 + __high2float(c001) * w001
                       + __high2float(c010) * w010 + __high2float(c011) * w011
                       + __high2float(c100) * w100 + __high2float(c101) * w101
                       + __high2float(c110) * w110 + __high2float(c111) * w111;
    }

    const float4* __restrict__ w1k = (const float4*)(sW1 + assign * W1S);
    const float4* __restrict__ b1k = (const float4*)(sB1 + assign * BS);
    const float4* __restrict__ w2k = (const float4*)(sW2 + assign * BS);

    float outv = sB2[assign];
    #pragma unroll
    for (int j4 = 0; j4 < HID / 4; ++j4) {
        float4 a = b1k[j4];
        #pragma unroll
        for (int i = 0; i < INF; ++i) {
            const float4 w = w1k[i * (HID / 4) + j4];
            const float e = enc[i];
            a.x = fmaf(e, w.x, a.x);
            a.y = fmaf(e, w.y, a.y);
            a.z = fmaf(e, w.z, a.z);
            a.w = fmaf(e, w.w, a.w);
        }
        a.x = fmaxf(a.x, 0.f); a.y = fmaxf(a.y, 0.f);
        a.z = fmaxf(a.z, 0.f); a.w = fmaxf(a.w, 0.f);
        const float4 w2v = w2k[j4];
        outv = fmaf(a.x, w2v.x, outv);
        outv = fmaf(a.y, w2v.y, outv);
        outv = fmaf(a.z, w2v.z, outv);
        outv = fmaf(a.w, w2v.w, outv);
    }

    out[gid] = expf(outv);
}

// ---------------- Fallback tier 2: fp32 (round-0 kernel) --------------------
__global__ __launch_bounds__(256) void propnet_density_kernel_f(
    const float* __restrict__ positions,
    const float* __restrict__ centroids,
    const float* __restrict__ tables,
    const float* __restrict__ W1,
    const float* __restrict__ b1,
    const float* __restrict__ W2,
    const float* __restrict__ b2,
    float* __restrict__ out,
    int npts)
{
    __shared__ float sW1[KF * W1S];
    __shared__ float sB1[KF * BS];
    __shared__ float sW2[KF * BS];
    __shared__ float sB2[KF];
    __shared__ float sC[KF * 3];

    const int tid = threadIdx.x;

    for (int idx = tid; idx < KF * INF * HID; idx += blockDim.x) {
        int k = idx >> 10;
        int r = idx & 1023;
        sW1[k * W1S + r] = W1[idx];
    }
    for (int idx = tid; idx < KF * HID; idx += blockDim.x) {
        int k = idx >> 6;
        int r = idx & 63;
        sB1[k * BS + r] = b1[idx];
        sW2[k * BS + r] = W2[idx];
    }
    if (tid < KF) sB2[tid] = b2[tid];
    if (tid < KF * 3) sC[tid] = centroids[tid];
    __syncthreads();

    const int gid = blockIdx.x * blockDim.x + tid;
    if (gid >= npts) return;

    const float px = positions[gid * 3 + 0];
    const float py = positions[gid * 3 + 1];
    const float pz = positions[gid * 3 + 2];

    int assign = 0;
    float best = 1e30f;
    #pragma unroll
    for (int k = 0; k < KF; ++k) {
        float dx = px - sC[k * 3 + 0];
        float dy = py - sC[k * 3 + 1];
        float dz = pz - sC[k * 3 + 2];
        float d2 = fmaf(dx, dx, fmaf(dy, dy, dz * dz));
        bool lt = d2 < best;
        assign = lt ? k : assign;
        best = lt ? d2 : best;
    }

    float enc[INF];
    const float2* __restrict__ tab =
        (const float2*)tables + (size_t)assign * (LL * (size_t)TT);

    #pragma unroll
    for (int l = 0; l < LL; ++l) {
        const float res = (float)(16 << l);
        const float sx = px * res, sy = py * res, sz = pz * res;
        const float fx = floorf(sx), fy = floorf(sy), fz = floorf(sz);
        const float wx = sx - fx, wy = sy - fy, wz = sz - fz;
        const unsigned ix = (unsigned)(int)fx;
        const unsigned iy = (unsigned)(int)fy;
        const unsigned iz = (unsigned)(int)fz;

        const float2* __restrict__ tl = tab + (size_t)l * TT;

        const unsigned hx0 = ix;
        const unsigned hx1 = ix + 1u;
        const unsigned hy0 = iy * 2654435761u;
        const unsigned hy1 = (iy + 1u) * 2654435761u;
        const unsigned hz0 = iz * 805459861u;
        const unsigned hz1 = (iz + 1u) * 805459861u;
        const unsigned M = TT - 1;

        const float2 c000 = tl[(hx0 ^ hy0 ^ hz0) & M];
        const float2 c001 = tl[(hx0 ^ hy0 ^ hz1) & M];
        const float2 c010 = tl[(hx0 ^ hy1 ^ hz0) & M];
        const float2 c011 = tl[(hx0 ^ hy1 ^ hz1) & M];
        const float2 c100 = tl[(hx1 ^ hy0 ^ hz0) & M];
        const float2 c101 = tl[(hx1 ^ hy0 ^ hz1) & M];
        const float2 c110 = tl[(hx1 ^ hy1 ^ hz0) & M];
        const float2 c111 = tl[(hx1 ^ hy1 ^ hz1) & M];

        const float ux = 1.f - wx, uy = 1.f - wy, uz = 1.f - wz;
        const float w000 = ux * uy * uz, w001 = ux * uy * wz;
        const float w010 = ux * wy * uz, w011 = ux * wy * wz;
        const float w100 = wx * uy * uz, w101 = wx * uy * wz;
        const float w110 = wx * wy * uz, w111 = wx * wy * wz;

        enc[l * 2 + 0] = c000.x * w000 + c001.x * w001 + c010.x * w010 + c011.x * w011
                       + c100.x * w100 + c101.x * w101 + c110.x * w110 + c111.x * w111;
        enc[l * 2 + 1] = c000.y * w000 + c001.y * w001 + c010.y * w010 + c011.y * w011
                       + c100.y * w100 + c101.y * w101 + c110.y * w110 + c111.y * w111;
    }

    const float4* __restrict__ w1k = (const float4*)(sW1 + assign * W1S);
    const float4* __restrict__ b1k = (const float4*)(sB1 + assign * BS);
    const float4* __restrict__ w2k = (const float4*)(sW2 + assign * BS);

    float outv = sB2[assign];
    #pragma unroll
    for (int j4 = 0; j4 < HID / 4; ++j4) {
        float4 a = b1k[j4];
        #pragma unroll
        for (int i = 0; i < INF; ++i) {
            const float4 w = w1k[i * (HID / 4) + j4];
            const float e = enc[i];
            a.x = fmaf(e, w.x, a.x);
            a.y = fmaf(e, w.y, a.y);
            a.z = fmaf(e, w.z, a.z);
            a.w = fmaf(e, w.w, a.w);
        }
        a.x = fmaxf(a.x, 0.f); a.y = fmaxf(a.y, 0.f);
        a.z = fmaxf(a.z, 0.f); a.w = fmaxf(a.w, 0.f);
        const float4 w2v = w2k[j4];
        outv = fmaf(a.x, w2v.x, outv);
        outv = fmaf(a.y, w2v.y, outv);
        outv = fmaf(a.z, w2v.z, outv);
        outv = fmaf(a.w, w2v.w, outv);
    }

    out[gid] = expf(outv);
}

extern "C" void kernel_launch(void* const* d_in, const int* in_sizes, int n_in,
                              void* d_out, int out_size, void* d_ws, size_t ws_size,
                              hipStream_t stream) {
    const float* positions = (const float*)d_in[0];
    const float* centroids = (const float*)d_in[1];
    const float* tables    = (const float*)d_in[2];
    const float* W1        = (const float*)d_in[3];
    const float* b1        = (const float*)d_in[4];
    const float* W2        = (const float*)d_in[5];
    const float* b2        = (const float*)d_in[6];
    float* out = (float*)d_out;

    const int npts = in_sizes[0] / 3;
    const int block = 256;
    const int nb = (npts + block - 1) / block;        // 256-pt blocks (phase 1)

    const size_t need_h    = TAB_BYTES;                                   // 64 Mi
    const size_t need_full = TAB_BYTES + 256 + (size_t)KF * npts * 4;     // ~80 Mi

    if (ws_size >= need_full && d_ws != nullptr) {
        char* base = (char*)d_ws;
        __half2*  wsTab   = (__half2*)base;
        unsigned* cursors = (unsigned*)(base + TAB_BYTES);
        unsigned* indices = (unsigned*)(base + TAB_BYTES + 256);

        const int rthreads = NENT / 8;
        repack_tables_fp16<<<rthreads / 256, 256, 0, stream>>>(
            (const float4*)tables, (uint4*)wsTab, rthreads);
        zero_cursors<<<1, 64, 0, stream>>>(cursors);
        bucket_points<<<nb, block, 0, stream>>>(
            positions, centroids, cursors, indices, npts);

        // Balanced chunked-XCD dispatch over 512-pt padded virtual blocks:
        const int nb2 = (npts + 511) / 512;
        const int G = ((nb2 + KF + 7) / 8) * 8;
        const int cpx = G / 8;
        propnet_density_balanced<<<G, block, 0, stream>>>(
            positions, wsTab, W1, b1, W2, b2, cursors, indices, out, npts, cpx);
    } else if (ws_size >= need_h && d_ws != nullptr) {
        const int rthreads = NENT / 8;
        repack_tables_fp16<<<rthreads / 256, 256, 0, stream>>>(
            (const float4*)tables, (uint4*)d_ws, rthreads);
        propnet_density_kernel_h<<<nb, block, 0, stream>>>(
            positions, centroids, (const __half2*)d_ws, W1, b1, W2, b2, out, npts);
    } else {
        propnet_density_kernel_f<<<nb, block, 0, stream>>>(
            positions, centroids, tables, W1, b1, W2, b2, out, npts);
    }
}

// Round 13
// 444.538 us; speedup vs baseline: 2.5680x; 2.5680x over previous
//
#include <hip/hip_runtime.h>
#include <hip/hip_fp16.h>
#include <math.h>

#define KF 8
#define LL 8
#define TT (1 << 18)
#define FF 2
#define HID 64
#define INF 16          // L*F = MLP input dim
// Legacy strides for the unbucketed fallback kernels:
#define W1S 1056
#define BS  68

#define NENT (KF * LL * TT)           // 16,777,216 table entries
#define TAB_BYTES ((size_t)NENT * 4)  // half2 table: 64 MiB

#define NCELL 4096                    // 16^3 spatial sort cells
#define NKEY  (KF * NCELL)            // 32768 (cluster, cell) keys

// ---------------------------------------------------------------------------
// Round-13: r12's two-point ILP attempt SPILLED (VGPR 256, WRITE_SIZE 886MB
// scratch) — per-wave ILP is a dead lever on this compiler (serialize r9 /
// crash r10,r11 / spill r12). Main kernel reverts to r8's verified form.
// New lever: SPATIAL SORT of each cluster's bucket. Arrival order is
// spatially random -> 64 lanes hit 64 unrelated cells every level. Sorting
// by 16^3 cell makes consecutive points share cells: levels 0-2's corner
// gathers collapse to identical addresses (same corner -> same hash ->
// broadcast-merge), and temporal reuse lets levels 5-7 (3MB/cluster) stay
// L2-resident. Main kernel is BYTE-IDENTICAL to r8 — only the order inside
// indices[] changes. Passes: zero-hist -> assign+hist -> 1-block scan ->
// scatter (~+20us, replacing ~15us bucket).
// Pre-commit: main kernel >=130us with sorted order => request-service wall
// proven => declare roofline.
// ---------------------------------------------------------------------------

__global__ __launch_bounds__(256) void repack_tables_fp16(
    const float4* __restrict__ src, uint4* __restrict__ dst, int nthreads)
{
    const int gid = blockIdx.x * blockDim.x + threadIdx.x;
    if (gid >= nthreads) return;
    const size_t b = (size_t)gid * 4;            // float4 index (2 entries each)

    const float4 f0 = src[b + 0];
    const float4 f1 = src[b + 1];
    const float4 f2 = src[b + 2];
    const float4 f3 = src[b + 3];

    uint4 d0, d1;
    {
        __half2 h;
        h = __floats2half2_rn(f0.x, f0.y); d0.x = *reinterpret_cast<unsigned*>(&h);
        h = __floats2half2_rn(f0.z, f0.w); d0.y = *reinterpret_cast<unsigned*>(&h);
        h = __floats2half2_rn(f1.x, f1.y); d0.z = *reinterpret_cast<unsigned*>(&h);
        h = __floats2half2_rn(f1.z, f1.w); d0.w = *reinterpret_cast<unsigned*>(&h);
        h = __floats2half2_rn(f2.x, f2.y); d1.x = *reinterpret_cast<unsigned*>(&h);
        h = __floats2half2_rn(f2.z, f2.w); d1.y = *reinterpret_cast<unsigned*>(&h);
        h = __floats2half2_rn(f3.x, f3.y); d1.z = *reinterpret_cast<unsigned*>(&h);
        h = __floats2half2_rn(f3.z, f3.w); d1.w = *reinterpret_cast<unsigned*>(&h);
    }
    dst[(size_t)gid * 2 + 0] = d0;
    dst[(size_t)gid * 2 + 1] = d1;
}

// ---- sorted-bucketing passes ----------------------------------------------

__device__ __forceinline__ int argmin_cluster(
    const float* sC, float px, float py, float pz)
{
    int assign = 0;
    float best = 1e30f;
    #pragma unroll
    for (int k = 0; k < KF; ++k) {
        float dx = px - sC[k * 3 + 0];
        float dy = py - sC[k * 3 + 1];
        float dz = pz - sC[k * 3 + 2];
        float d2 = fmaf(dx, dx, fmaf(dy, dy, dz * dz));
        bool lt = d2 < best;
        assign = lt ? k : assign;
        best = lt ? d2 : best;
    }
    return assign;
}

__device__ __forceinline__ unsigned cell16(float px, float py, float pz)
{
    int cx = (int)(px * 16.f); cx = cx < 0 ? 0 : (cx > 15 ? 15 : cx);
    int cy = (int)(py * 16.f); cy = cy < 0 ? 0 : (cy > 15 ? 15 : cy);
    int cz = (int)(pz * 16.f); cz = cz < 0 ? 0 : (cz > 15 ? 15 : cz);
    return (unsigned)(cx + cy * 16 + cz * 256);
}

__global__ __launch_bounds__(256) void zero_hist(unsigned* __restrict__ hist)
{
    const int gid = blockIdx.x * blockDim.x + threadIdx.x;
    if (gid < NKEY) hist[gid] = 0u;
}

__global__ __launch_bounds__(256) void assign_hist(
    const float* __restrict__ positions,
    const float* __restrict__ centroids,
    unsigned* __restrict__ hist, int npts)
{
    __shared__ float sC[KF * 3];
    const int tid = threadIdx.x;
    if (tid < KF * 3) sC[tid] = centroids[tid];
    __syncthreads();

    const int gid = blockIdx.x * blockDim.x + tid;
    if (gid >= npts) return;
    const float px = positions[gid * 3 + 0];
    const float py = positions[gid * 3 + 1];
    const float pz = positions[gid * 3 + 2];
    const int k = argmin_cluster(sC, px, py, pz);
    const unsigned key = (unsigned)k * NCELL + cell16(px, py, pz);
    atomicAdd(&hist[key], 1u);
}

// Single-block scan: hist counts -> global exclusive prefixes.
// cursors[0..7] = per-cluster totals; cursors[8..15] = cluster start prefix.
__global__ __launch_bounds__(1024) void scan_hist(
    unsigned* __restrict__ hist, unsigned* __restrict__ cursors, int npts)
{
    __shared__ unsigned s[1024];
    __shared__ unsigned cs[KF];
    const int t = threadIdx.x;
    const int base = t * (NKEY / 1024);          // 32 keys per thread

    unsigned loc[NKEY / 1024];
    unsigned sum = 0;
    #pragma unroll
    for (int i = 0; i < NKEY / 1024; ++i) { loc[i] = hist[base + i]; sum += loc[i]; }
    s[t] = sum;
    __syncthreads();

    // Hillis-Steele inclusive scan over the 1024 chunk sums.
    for (int off = 1; off < 1024; off <<= 1) {
        unsigned v = (t >= off) ? s[t - off] : 0u;
        __syncthreads();
        s[t] += v;
        __syncthreads();
    }
    const unsigned excl = s[t] - sum;            // exclusive prefix of chunk

    unsigned run = excl;
    #pragma unroll
    for (int i = 0; i < NKEY / 1024; ++i) { hist[base + i] = run; run += loc[i]; }

    // cluster k starts at key k*NCELL = chunk (k*NCELL/32) = thread k*128
    if ((t & 127) == 0 && (t >> 7) < KF) cs[t >> 7] = excl;
    __syncthreads();
    if (t < KF) {
        cursors[8 + t] = cs[t];
        cursors[t] = ((t == KF - 1) ? (unsigned)npts : cs[t + 1]) - cs[t];
    }
}

__global__ __launch_bounds__(256) void scatter_sorted(
    const float* __restrict__ positions,
    const float* __restrict__ centroids,
    unsigned* __restrict__ hist,              // exclusive prefixes (bumped)
    const unsigned* __restrict__ cursors,     // [8..15] = cluster starts
    unsigned* __restrict__ indices, int npts)
{
    __shared__ float sC[KF * 3];
    const int tid = threadIdx.x;
    if (tid < KF * 3) sC[tid] = centroids[tid];
    __syncthreads();

    const int gid = blockIdx.x * blockDim.x + tid;
    if (gid >= npts) return;
    const float px = positions[gid * 3 + 0];
    const float py = positions[gid * 3 + 1];
    const float pz = positions[gid * 3 + 2];
    const int k = argmin_cluster(sC, px, py, pz);
    const unsigned key = (unsigned)k * NCELL + cell16(px, py, pz);
    const unsigned pos = atomicAdd(&hist[key], 1u);     // global position
    const unsigned rank = pos - cursors[8 + k];         // rank within cluster
    indices[(size_t)k * npts + rank] = (unsigned)gid;
}

// Legacy phase 1 (unsorted bucket scatter) — fallback tier.
__global__ void zero_cursors(unsigned* __restrict__ cursors)
{
    if (threadIdx.x < KF) cursors[threadIdx.x] = 0u;
}

__global__ __launch_bounds__(256) void bucket_points(
    const float* __restrict__ positions,
    const float* __restrict__ centroids,
    unsigned* __restrict__ cursors,
    unsigned* __restrict__ indices,
    int npts)
{
    __shared__ float sC[KF * 3];
    __shared__ unsigned lcnt[KF];
    __shared__ unsigned lbase[KF];

    const int tid = threadIdx.x;
    if (tid < KF * 3) sC[tid] = centroids[tid];
    if (tid < KF) lcnt[tid] = 0u;
    __syncthreads();

    const int gid = blockIdx.x * blockDim.x + tid;
    int assign = 0;
    unsigned lrank = 0;
    const bool valid = (gid < npts);
    if (valid) {
        const float px = positions[gid * 3 + 0];
        const float py = positions[gid * 3 + 1];
        const float pz = positions[gid * 3 + 2];
        assign = argmin_cluster(sC, px, py, pz);
        lrank = atomicAdd(&lcnt[assign], 1u);
    }
    __syncthreads();
    if (tid < KF) lbase[tid] = atomicAdd(&cursors[tid], lcnt[tid]);
    __syncthreads();
    if (valid)
        indices[(size_t)assign * npts + lbase[assign] + lrank] = (unsigned)gid;
}

// Phase 2: balanced chunked-XCD density kernel — EXACT r8 code (verified).
__global__ __launch_bounds__(256) void propnet_density_balanced(
    const float* __restrict__ positions,
    const __half2* __restrict__ tables,       // repacked half2 table (ws)
    const float* __restrict__ W1,
    const float* __restrict__ b1,
    const float* __restrict__ W2,
    const float* __restrict__ b2,
    const unsigned* __restrict__ cursors,     // [0..7] per-cluster counts
    const unsigned* __restrict__ indices,     // [KF * npts]
    float* __restrict__ out,
    int npts, int cpx)
{
    __shared__ float sW1[INF * HID];          // 4096 B, single cluster
    __shared__ float sB1[HID];
    __shared__ float sW2[HID];
    __shared__ unsigned snk[KF];

    const int tid = threadIdx.x;
    const int b = blockIdx.x;
    const int v = (b & 7) * cpx + (b >> 3);   // chunked XCD swizzle

    if (tid < KF) snk[tid] = cursors[tid];
    __syncthreads();

    // Locate (cluster k, slot) for virtual block v in the padded-block space.
    int k = -1;
    unsigned slot = 0, nk = 0, acc = 0;
    #pragma unroll
    for (int kk = 0; kk < KF; ++kk) {
        const unsigned n = snk[kk];
        const unsigned nbk = (n + 255u) >> 8;        // padded blocks for kk
        if (k < 0 && (unsigned)v < acc + nbk) {
            k = kk; slot = (unsigned)v - acc; nk = n;
        }
        acc += nbk;
    }
    if (k < 0) return;                               // v beyond vtotal (few)

    // Single-cluster weight staging (coalesced; wave-uniform reads later).
    for (int idx = tid; idx < INF * HID; idx += blockDim.x)
        sW1[idx] = W1[k * (INF * HID) + idx];
    if (tid < HID) {
        sB1[tid] = b1[k * HID + tid];
        sW2[tid] = W2[k * HID + tid];
    }
    __syncthreads();

    const unsigned rank = slot * 256u + (unsigned)tid;
    if (rank >= nk) return;                          // tail threads only
    const unsigned pidx = indices[(size_t)k * npts + rank];

    const float px = positions[pidx * 3 + 0];
    const float py = positions[pidx * 3 + 1];
    const float pz = positions[pidx * 3 + 2];

    // ---- multiresolution hash encoding (half2 gathers, uniform table base) ----
    float enc[INF];
    const __half2* __restrict__ tab = tables + (size_t)k * (LL * (size_t)TT);

    #pragma unroll
    for (int l = 0; l < LL; ++l) {
        const float res = (float)(16 << l);
        const float sx = px * res, sy = py * res, sz = pz * res;
        const float fx = floorf(sx), fy = floorf(sy), fz = floorf(sz);
        const float wx = sx - fx, wy = sy - fy, wz = sz - fz;
        const unsigned ix = (unsigned)(int)fx;
        const unsigned iy = (unsigned)(int)fy;
        const unsigned iz = (unsigned)(int)fz;

        const __half2* __restrict__ tl = tab + (size_t)l * TT;

        const unsigned hx0 = ix;                         // prime 1
        const unsigned hx1 = ix + 1u;
        const unsigned hy0 = iy * 2654435761u;
        const unsigned hy1 = (iy + 1u) * 2654435761u;
        const unsigned hz0 = iz * 805459861u;
        const unsigned hz1 = (iz + 1u) * 805459861u;
        const unsigned M = TT - 1;

        // 8 independent 4B gathers — keep them all in flight
        const __half2 c000 = tl[(hx0 ^ hy0 ^ hz0) & M];
        const __half2 c001 = tl[(hx0 ^ hy0 ^ hz1) & M];
        const __half2 c010 = tl[(hx0 ^ hy1 ^ hz0) & M];
        const __half2 c011 = tl[(hx0 ^ hy1 ^ hz1) & M];
        const __half2 c100 = tl[(hx1 ^ hy0 ^ hz0) & M];
        const __half2 c101 = tl[(hx1 ^ hy0 ^ hz1) & M];
        const __half2 c110 = tl[(hx1 ^ hy1 ^ hz0) & M];
        const __half2 c111 = tl[(hx1 ^ hy1 ^ hz1) & M];

        const float ux = 1.f - wx, uy = 1.f - wy, uz = 1.f - wz;
        const float w000 = ux * uy * uz, w001 = ux * uy * wz;
        const float w010 = ux * wy * uz, w011 = ux * wy * wz;
        const float w100 = wx * uy * uz, w101 = wx * uy * wz;
        const float w110 = wx * wy * uz, w111 = wx * wy * wz;

        enc[l * 2 + 0] = __low2float(c000) * w000 + __low2float(c001) * w001
                       + __low2float(c010) * w010 + __low2float(c011) * w011
                       + __low2float(c100) * w100 + __low2float(c101) * w101
                       + __low2float(c110) * w110 + __low2float(c111) * w111;
        enc[l * 2 + 1] = __high2float(c000) * w000 + __high2float(c001) * w001
                       + __high2float(c010) * w010 + __high2float(c011) * w011
                       + __high2float(c100) * w100 + __high2float(c101) * w101
                       + __high2float(c110) * w110 + __high2float(c111) * w111;
    }

    // ---- MLP (single-cluster weights, wave-uniform LDS broadcasts) ----
    const float4* __restrict__ w1k = (const float4*)sW1;
    const float4* __restrict__ b1k = (const float4*)sB1;
    const float4* __restrict__ w2k = (const float4*)sW2;

    float outv = b2[k];
    #pragma unroll
    for (int j4 = 0; j4 < HID / 4; ++j4) {
        float4 a = b1k[j4];
        #pragma unroll
        for (int i = 0; i < INF; ++i) {
            const float4 w = w1k[i * (HID / 4) + j4];
            const float e = enc[i];
            a.x = fmaf(e, w.x, a.x);
            a.y = fmaf(e, w.y, a.y);
            a.z = fmaf(e, w.z, a.z);
            a.w = fmaf(e, w.w, a.w);
        }
        a.x = fmaxf(a.x, 0.f); a.y = fmaxf(a.y, 0.f);
        a.z = fmaxf(a.z, 0.f); a.w = fmaxf(a.w, 0.f);
        const float4 w2v = w2k[j4];
        outv = fmaf(a.x, w2v.x, outv);
        outv = fmaf(a.y, w2v.y, outv);
        outv = fmaf(a.z, w2v.z, outv);
        outv = fmaf(a.w, w2v.w, outv);
    }

    out[pidx] = expf(outv);
}

// ---------------- Fallback tier: unbucketed fp16 (round-5/6 kernel) ---------
__global__ __launch_bounds__(256) void propnet_density_kernel_h(
    const float* __restrict__ positions,
    const float* __restrict__ centroids,
    const __half2* __restrict__ tables,
    const float* __restrict__ W1,
    const float* __restrict__ b1,
    const float* __restrict__ W2,
    const float* __restrict__ b2,
    float* __restrict__ out,
    int npts)
{
    __shared__ float sW1[KF * W1S];
    __shared__ float sB1[KF * BS];
    __shared__ float sW2[KF * BS];
    __shared__ float sB2[KF];
    __shared__ float sC[KF * 3];

    const int tid = threadIdx.x;

    for (int idx = tid; idx < KF * INF * HID; idx += blockDim.x) {
        int k = idx >> 10;
        int r = idx & 1023;
        sW1[k * W1S + r] = W1[idx];
    }
    for (int idx = tid; idx < KF * HID; idx += blockDim.x) {
        int k = idx >> 6;
        int r = idx & 63;
        sB1[k * BS + r] = b1[idx];
        sW2[k * BS + r] = W2[idx];
    }
    if (tid < KF) sB2[tid] = b2[tid];
    if (tid < KF * 3) sC[tid] = centroids[tid];
    __syncthreads();

    const int gid = blockIdx.x * blockDim.x + tid;
    if (gid >= npts) return;

    const float px = positions[gid * 3 + 0];
    const float py = positions[gid * 3 + 1];
    const float pz = positions[gid * 3 + 2];

    int assign = argmin_cluster(sC, px, py, pz);

    float enc[INF];
    const __half2* __restrict__ tab =
        tables + (size_t)assign * (LL * (size_t)TT);

    #pragma unroll
    for (int l = 0; l < LL; ++l) {
        const float res = (float)(16 << l);
        const float sx = px * res, sy = py * res, sz = pz * res;
        const float fx = floorf(sx), fy = floorf(sy), fz = floorf(sz);
        const float wx = sx - fx, wy = sy - fy, wz = sz - fz;
        const unsigned ix = (unsigned)(int)fx;
        const unsigned iy = (unsigned)(int)fy;
        const unsigned iz = (unsigned)(int)fz;

        const __half2* __restrict__ tl = tab + (size_t)l * TT;

        const unsigned hx0 = ix;
        const unsigned hx1 = ix + 1u;
        const unsigned hy0 = iy * 2654435761u;
        const unsigned hy1 = (iy + 1u) * 2654435761u;
        const unsigned hz0 = iz * 805459861u;
        const unsigned hz1 = (iz + 1u) * 805459861u;
        const unsigned M = TT - 1;

        const __half2 c000 = tl[(hx0 ^ hy0 ^ hz0) & M];
        const __half2 c001 = tl[(hx0 ^ hy0 ^ hz1) & M];
        const __half2 c010 = tl[(hx0 ^ hy1 ^ hz0) & M];
        const __half2 c011 = tl[(hx0 ^ hy1 ^ hz1) & M];
        const __half2 c100 = tl[(hx1 ^ hy0 ^ hz0) & M];
        const __half2 c101 = tl[(hx1 ^ hy0 ^ hz1) & M];
        const __half2 c110 = tl[(hx1 ^ hy1 ^ hz0) & M];
        const __half2 c111 = tl[(hx1 ^ hy1 ^ hz1) & M];

        const float ux = 1.f - wx, uy = 1.f - wy, uz = 1.f - wz;
        const float w000 = ux * uy * uz, w001 = ux * uy * wz;
        const float w010 = ux * wy * uz, w011 = ux * wy * wz;
        const float w100 = wx * uy * uz, w101 = wx * uy * wz;
        const float w110 = wx * wy * uz, w111 = wx * wy * wz;

        enc[l * 2 + 0] = __low2float(c000) * w000 + __low2float(c001) * w001
                       + __low2float(c010) * w010 + __low2float(c011) * w011
                       + __low2float(c100) * w100 + __low2float(c101) * w101
                       + __low2float(c110) * w110 + __low2float(c111) * w111;
        enc[l * 2 + 1] = __high2float(c000) * w000 + __high2float(c001) * w001
                       + __high2float(c010) * w010 + __high2float(c011) * w011
                       + __high2float(c100) * w100 + __high2float(c101) * w101
                       + __high2float(c110) * w110 + __high2float(c111) * w111;
    }

    const float4* __restrict__ w1k = (const float4*)(sW1 + assign * W1S);
    const float4* __restrict__ b1k = (const float4*)(sB1 + assign * BS);
    const float4* __restrict__ w2k = (const float4*)(sW2 + assign * BS);

    float outv = sB2[assign];
    #pragma unroll
    for (int j4 = 0; j4 < HID / 4; ++j4) {
        float4 a = b1k[j4];
        #pragma unroll
        for (int i = 0; i < INF; ++i) {
            const float4 w = w1k[i * (HID / 4) + j4];
            const float e = enc[i];
            a.x = fmaf(e, w.x, a.x);
            a.y = fmaf(e, w.y, a.y);
            a.z = fmaf(e, w.z, a.z);
            a.w = fmaf(e, w.w, a.w);
        }
        a.x = fmaxf(a.x, 0.f); a.y = fmaxf(a.y, 0.f);
        a.z = fmaxf(a.z, 0.f); a.w = fmaxf(a.w, 0.f);
        const float4 w2v = w2k[j4];
        outv = fmaf(a.x, w2v.x, outv);
        outv = fmaf(a.y, w2v.y, outv);
        outv = fmaf(a.z, w2v.z, outv);
        outv = fmaf(a.w, w2v.w, outv);
    }

    out[gid] = expf(outv);
}

// ---------------- Fallback tier: fp32 (round-0 kernel) ----------------------
__global__ __launch_bounds__(256) void propnet_density_kernel_f(
    const float* __restrict__ positions,
    const float* __restrict__ centroids,
    const float* __restrict__ tables,
    const float* __restrict__ W1,
    const float* __restrict__ b1,
    const float* __restrict__ W2,
    const float* __restrict__ b2,
    float* __restrict__ out,
    int npts)
{
    __shared__ float sW1[KF * W1S];
    __shared__ float sB1[KF * BS];
    __shared__ float sW2[KF * BS];
    __shared__ float sB2[KF];
    __shared__ float sC[KF * 3];

    const int tid = threadIdx.x;

    for (int idx = tid; idx < KF * INF * HID; idx += blockDim.x) {
        int k = idx >> 10;
        int r = idx & 1023;
        sW1[k * W1S + r] = W1[idx];
    }
    for (int idx = tid; idx < KF * HID; idx += blockDim.x) {
        int k = idx >> 6;
        int r = idx & 63;
        sB1[k * BS + r] = b1[idx];
        sW2[k * BS + r] = W2[idx];
    }
    if (tid < KF) sB2[tid] = b2[tid];
    if (tid < KF * 3) sC[tid] = centroids[tid];
    __syncthreads();

    const int gid = blockIdx.x * blockDim.x + tid;
    if (gid >= npts) return;

    const float px = positions[gid * 3 + 0];
    const float py = positions[gid * 3 + 1];
    const float pz = positions[gid * 3 + 2];

    int assign = argmin_cluster(sC, px, py, pz);

    float enc[INF];
    const float2* __restrict__ tab =
        (const float2*)tables + (size_t)assign * (LL * (size_t)TT);

    #pragma unroll
    for (int l = 0; l < LL; ++l) {
        const float res = (float)(16 << l);
        const float sx = px * res, sy = py * res, sz = pz * res;
        const float fx = floorf(sx), fy = floorf(sy), fz = floorf(sz);
        const float wx = sx - fx, wy = sy - fy, wz = sz - fz;
        const unsigned ix = (unsigned)(int)fx;
        const unsigned iy = (unsigned)(int)fy;
        const unsigned iz = (unsigned)(int)fz;

        const float2* __restrict__ tl = tab + (size_t)l * TT;

        const unsigned hx0 = ix;
        const unsigned hx1 = ix + 1u;
        const unsigned hy0 = iy * 2654435761u;
        const unsigned hy1 = (iy + 1u) * 2654435761u;
        const unsigned hz0 = iz * 805459861u;
        const unsigned hz1 = (iz + 1u) * 805459861u;
        const unsigned M = TT - 1;

        const float2 c000 = tl[(hx0 ^ hy0 ^ hz0) & M];
        const float2 c001 = tl[(hx0 ^ hy0 ^ hz1) & M];
        const float2 c010 = tl[(hx0 ^ hy1 ^ hz0) & M];
        const float2 c011 = tl[(hx0 ^ hy1 ^ hz1) & M];
        const float2 c100 = tl[(hx1 ^ hy0 ^ hz0) & M];
        const float2 c101 = tl[(hx1 ^ hy0 ^ hz1) & M];
        const float2 c110 = tl[(hx1 ^ hy1 ^ hz0) & M];
        const float2 c111 = tl[(hx1 ^ hy1 ^ hz1) & M];

        const float ux = 1.f - wx, uy = 1.f - wy, uz = 1.f - wz;
        const float w000 = ux * uy * uz, w001 = ux * uy * wz;
        const float w010 = ux * wy * uz, w011 = ux * wy * wz;
        const float w100 = wx * uy * uz, w101 = wx * uy * wz;
        const float w110 = wx * wy * uz, w111 = wx * wy * wz;

        enc[l * 2 + 0] = c000.x * w000 + c001.x * w001 + c010.x * w010 + c011.x * w011
                       + c100.x * w100 + c101.x * w101 + c110.x * w110 + c111.x * w111;
        enc[l * 2 + 1] = c000.y * w000 + c001.y * w001 + c010.y * w010 + c011.y * w011
                       + c100.y * w100 + c101.y * w101 + c110.y * w110 + c111.y * w111;
    }

    const float4* __restrict__ w1k = (const float4*)(sW1 + assign * W1S);
    const float4* __restrict__ b1k = (const float4*)(sB1 + assign * BS);
    const float4* __restrict__ w2k = (const float4*)(sW2 + assign * BS);

    float outv = sB2[assign];
    #pragma unroll
    for (int j4 = 0; j4 < HID / 4; ++j4) {
        float4 a = b1k[j4];
        #pragma unroll
        for (int i = 0; i < INF; ++i) {
            const float4 w = w1k[i * (HID / 4) + j4];
            const float e = enc[i];
            a.x = fmaf(e, w.x, a.x);
            a.y = fmaf(e, w.y, a.y);
            a.z = fmaf(e, w.z, a.z);
            a.w = fmaf(e, w.w, a.w);
        }
        a.x = fmaxf(a.x, 0.f); a.y = fmaxf(a.y, 0.f);
        a.z = fmaxf(a.z, 0.f); a.w = fmaxf(a.w, 0.f);
        const float4 w2v = w2k[j4];
        outv = fmaf(a.x, w2v.x, outv);
        outv = fmaf(a.y, w2v.y, outv);
        outv = fmaf(a.z, w2v.z, outv);
        outv = fmaf(a.w, w2v.w, outv);
    }

    out[gid] = expf(outv);
}

extern "C" void kernel_launch(void* const* d_in, const int* in_sizes, int n_in,
                              void* d_out, int out_size, void* d_ws, size_t ws_size,
                              hipStream_t stream) {
    const float* positions = (const float*)d_in[0];
    const float* centroids = (const float*)d_in[1];
    const float* tables    = (const float*)d_in[2];
    const float* W1        = (const float*)d_in[3];
    const float* b1        = (const float*)d_in[4];
    const float* W2        = (const float*)d_in[5];
    const float* b2        = (const float*)d_in[6];
    float* out = (float*)d_out;

    const int npts = in_sizes[0] / 3;
    const int block = 256;
    const int nb = (npts + block - 1) / block;

    const size_t idx_bytes   = (size_t)KF * npts * 4;
    const size_t need_h      = TAB_BYTES;                              // 64 Mi
    const size_t need_bucket = TAB_BYTES + 256 + idx_bytes;            // ~80 Mi
    const size_t need_sorted = need_bucket + (size_t)NKEY * 4;         // +128 Ki

    if (ws_size >= need_bucket && d_ws != nullptr) {
        char* base = (char*)d_ws;
        __half2*  wsTab   = (__half2*)base;
        unsigned* cursors = (unsigned*)(base + TAB_BYTES);   // 16 u32 used
        unsigned* indices = (unsigned*)(base + TAB_BYTES + 256);

        const int rthreads = NENT / 8;
        repack_tables_fp16<<<rthreads / 256, 256, 0, stream>>>(
            (const float4*)tables, (uint4*)wsTab, rthreads);

        if (ws_size >= need_sorted) {
            unsigned* hist = (unsigned*)(base + TAB_BYTES + 256 + idx_bytes);
            zero_hist<<<NKEY / 256, 256, 0, stream>>>(hist);
            assign_hist<<<nb, block, 0, stream>>>(positions, centroids, hist, npts);
            scan_hist<<<1, 1024, 0, stream>>>(hist, cursors, npts);
            scatter_sorted<<<nb, block, 0, stream>>>(
                positions, centroids, hist, cursors, indices, npts);
        } else {
            zero_cursors<<<1, 64, 0, stream>>>(cursors);
            bucket_points<<<nb, block, 0, stream>>>(
                positions, centroids, cursors, indices, npts);
        }

        const int G = ((nb + KF + 7) / 8) * 8;
        const int cpx = G / 8;
        propnet_density_balanced<<<G, block, 0, stream>>>(
            positions, wsTab, W1, b1, W2, b2, cursors, indices, out, npts, cpx);
    } else if (ws_size >= need_h && d_ws != nullptr) {
        const int rthreads = NENT / 8;
        repack_tables_fp16<<<rthreads / 256, 256, 0, stream>>>(
            (const float4*)tables, (uint4*)d_ws, rthreads);
        propnet_density_kernel_h<<<nb, block, 0, stream>>>(
            positions, centroids, (const __half2*)d_ws, W1, b1, W2, b2, out, npts);
    } else {
        propnet_density_kernel_f<<<nb, block, 0, stream>>>(
            positions, centroids, tables, W1, b1, W2, b2, out, npts);
    }
}

// Round 14
// 386.344 us; speedup vs baseline: 2.9548x; 1.1506x over previous
//
#include <hip/hip_runtime.h>
#include <hip/hip_fp16.h>
#include <math.h>

#define KF 8
#define LL 8
#define TT (1 << 18)
#define FF 2
#define HID 64
#define INF 16          // L*F = MLP input dim
// Legacy strides for the unbucketed fallback kernels:
#define W1S 1056
#define BS  68

#define NENT (KF * LL * TT)           // 16,777,216 table entries
#define TAB_BYTES ((size_t)NENT * 4)  // half2 table: 64 MiB

#define NCELL 4096                    // 16^3 spatial sort cells
#define NKEY  (KF * NCELL)            // 32768 (cluster, cell) keys

// ---------------------------------------------------------------------------
// Round-14: r13 validated the spatial-sort model (main 135->97us, FETCH
// 192->152MB) but the sort machinery cost ~147us and ate the win (total
// 366.8->444.5). Lean counting sort this round:
//   memsetAsync(hist)                      (no launch, no kernel)
//   assign_rank: ONE pass — argmin+cell, rank=atomicAdd(hist[key],1),
//                store packed = key<<17 | rank   (single atomic pass)
//   scan_hist:   counts -> in-place exclusive prefixes (+cluster starts)
//   place_sorted: read packed, pos = hist[key]+rank -> indices. NO atomics,
//                NO argmin recompute, coalesced reads.
// Main kernel BYTE-IDENTICAL to r13's 97us version.
// Pre-commit: total >=400 => sort cost irreducible => next round reverts to
// best known and declares the floor.
// ---------------------------------------------------------------------------

__global__ __launch_bounds__(256) void repack_tables_fp16(
    const float4* __restrict__ src, uint4* __restrict__ dst, int nthreads)
{
    const int gid = blockIdx.x * blockDim.x + threadIdx.x;
    if (gid >= nthreads) return;
    const size_t b = (size_t)gid * 4;            // float4 index (2 entries each)

    const float4 f0 = src[b + 0];
    const float4 f1 = src[b + 1];
    const float4 f2 = src[b + 2];
    const float4 f3 = src[b + 3];

    uint4 d0, d1;
    {
        __half2 h;
        h = __floats2half2_rn(f0.x, f0.y); d0.x = *reinterpret_cast<unsigned*>(&h);
        h = __floats2half2_rn(f0.z, f0.w); d0.y = *reinterpret_cast<unsigned*>(&h);
        h = __floats2half2_rn(f1.x, f1.y); d0.z = *reinterpret_cast<unsigned*>(&h);
        h = __floats2half2_rn(f1.z, f1.w); d0.w = *reinterpret_cast<unsigned*>(&h);
        h = __floats2half2_rn(f2.x, f2.y); d1.x = *reinterpret_cast<unsigned*>(&h);
        h = __floats2half2_rn(f2.z, f2.w); d1.y = *reinterpret_cast<unsigned*>(&h);
        h = __floats2half2_rn(f3.x, f3.y); d1.z = *reinterpret_cast<unsigned*>(&h);
        h = __floats2half2_rn(f3.z, f3.w); d1.w = *reinterpret_cast<unsigned*>(&h);
    }
    dst[(size_t)gid * 2 + 0] = d0;
    dst[(size_t)gid * 2 + 1] = d1;
}

// ---- lean sorted-bucketing ------------------------------------------------

__device__ __forceinline__ int argmin_cluster(
    const float* sC, float px, float py, float pz)
{
    int assign = 0;
    float best = 1e30f;
    #pragma unroll
    for (int k = 0; k < KF; ++k) {
        float dx = px - sC[k * 3 + 0];
        float dy = py - sC[k * 3 + 1];
        float dz = pz - sC[k * 3 + 2];
        float d2 = fmaf(dx, dx, fmaf(dy, dy, dz * dz));
        bool lt = d2 < best;
        assign = lt ? k : assign;
        best = lt ? d2 : best;
    }
    return assign;
}

__device__ __forceinline__ unsigned cell16(float px, float py, float pz)
{
    int cx = (int)(px * 16.f); cx = cx < 0 ? 0 : (cx > 15 ? 15 : cx);
    int cy = (int)(py * 16.f); cy = cy < 0 ? 0 : (cy > 15 ? 15 : cy);
    int cz = (int)(pz * 16.f); cz = cz < 0 ? 0 : (cz > 15 ? 15 : cz);
    return (unsigned)(cx + cy * 16 + cz * 256);
}

// One pass: argmin + cell + returning atomic rank; store key|rank packed.
__global__ __launch_bounds__(256) void assign_rank(
    const float* __restrict__ positions,
    const float* __restrict__ centroids,
    unsigned* __restrict__ hist,          // pre-zeroed [NKEY]
    unsigned* __restrict__ packed,        // [npts] key<<17 | rank
    int npts)
{
    __shared__ float sC[KF * 3];
    const int tid = threadIdx.x;
    if (tid < KF * 3) sC[tid] = centroids[tid];
    __syncthreads();

    const int gid = blockIdx.x * blockDim.x + tid;
    if (gid >= npts) return;
    const float px = positions[gid * 3 + 0];
    const float py = positions[gid * 3 + 1];
    const float pz = positions[gid * 3 + 2];
    const int k = argmin_cluster(sC, px, py, pz);
    const unsigned key = (unsigned)k * NCELL + cell16(px, py, pz);
    const unsigned rank = atomicAdd(&hist[key], 1u);     // returning
    packed[gid] = (key << 17) | rank;                    // rank < 2^17 always
}

// Single-block scan: hist counts -> in-place exclusive prefixes.
// cursors[0..7] = per-cluster totals; cursors[8..15] = cluster start prefix.
__global__ __launch_bounds__(1024) void scan_hist(
    unsigned* __restrict__ hist, unsigned* __restrict__ cursors, int npts)
{
    __shared__ unsigned s[1024];
    __shared__ unsigned cs[KF];
    const int t = threadIdx.x;
    const int base = t * (NKEY / 1024);          // 32 keys per thread

    unsigned loc[NKEY / 1024];
    unsigned sum = 0;
    #pragma unroll
    for (int i = 0; i < NKEY / 1024; ++i) { loc[i] = hist[base + i]; sum += loc[i]; }
    s[t] = sum;
    __syncthreads();

    // Hillis-Steele inclusive scan over the 1024 chunk sums.
    for (int off = 1; off < 1024; off <<= 1) {
        unsigned v = (t >= off) ? s[t - off] : 0u;
        __syncthreads();
        s[t] += v;
        __syncthreads();
    }
    const unsigned excl = s[t] - sum;            // exclusive prefix of chunk

    unsigned run = excl;
    #pragma unroll
    for (int i = 0; i < NKEY / 1024; ++i) { hist[base + i] = run; run += loc[i]; }

    // cluster k starts at key k*NCELL = chunk (k*NCELL/32) = thread k*128
    if ((t & 127) == 0 && (t >> 7) < KF) cs[t >> 7] = excl;
    __syncthreads();
    if (t < KF) {
        cursors[8 + t] = cs[t];
        cursors[t] = ((t == KF - 1) ? (unsigned)npts : cs[t + 1]) - cs[t];
    }
}

// No atomics, no argmin: pos = prefix[key] + rank; write indices.
__global__ __launch_bounds__(256) void place_sorted(
    const unsigned* __restrict__ packed,      // [npts]
    const unsigned* __restrict__ hist,        // exclusive prefixes
    const unsigned* __restrict__ cursors,     // [8..15] = cluster starts
    unsigned* __restrict__ indices, int npts)
{
    __shared__ unsigned sStart[KF];
    const int tid = threadIdx.x;
    if (tid < KF) sStart[tid] = cursors[8 + tid];
    __syncthreads();

    const int gid = blockIdx.x * blockDim.x + tid;
    if (gid >= npts) return;
    const unsigned p = packed[gid];
    const unsigned key = p >> 17;
    const unsigned rank = p & 0x1FFFFu;
    const unsigned k = key / NCELL;              // key>>12 (NCELL=4096)
    const unsigned pos = hist[key] + rank;       // global sorted position
    indices[(size_t)k * npts + (pos - sStart[k])] = (unsigned)gid;
}

// Legacy phase 1 (unsorted bucket scatter) — fallback tier.
__global__ void zero_cursors(unsigned* __restrict__ cursors)
{
    if (threadIdx.x < KF) cursors[threadIdx.x] = 0u;
}

__global__ __launch_bounds__(256) void bucket_points(
    const float* __restrict__ positions,
    const float* __restrict__ centroids,
    unsigned* __restrict__ cursors,
    unsigned* __restrict__ indices,
    int npts)
{
    __shared__ float sC[KF * 3];
    __shared__ unsigned lcnt[KF];
    __shared__ unsigned lbase[KF];

    const int tid = threadIdx.x;
    if (tid < KF * 3) sC[tid] = centroids[tid];
    if (tid < KF) lcnt[tid] = 0u;
    __syncthreads();

    const int gid = blockIdx.x * blockDim.x + tid;
    int assign = 0;
    unsigned lrank = 0;
    const bool valid = (gid < npts);
    if (valid) {
        const float px = positions[gid * 3 + 0];
        const float py = positions[gid * 3 + 1];
        const float pz = positions[gid * 3 + 2];
        assign = argmin_cluster(sC, px, py, pz);
        lrank = atomicAdd(&lcnt[assign], 1u);
    }
    __syncthreads();
    if (tid < KF) lbase[tid] = atomicAdd(&cursors[tid], lcnt[tid]);
    __syncthreads();
    if (valid)
        indices[(size_t)assign * npts + lbase[assign] + lrank] = (unsigned)gid;
}

// Phase 2: balanced chunked-XCD density kernel — EXACT r8/r13 code (verified).
__global__ __launch_bounds__(256) void propnet_density_balanced(
    const float* __restrict__ positions,
    const __half2* __restrict__ tables,       // repacked half2 table (ws)
    const float* __restrict__ W1,
    const float* __restrict__ b1,
    const float* __restrict__ W2,
    const float* __restrict__ b2,
    const unsigned* __restrict__ cursors,     // [0..7] per-cluster counts
    const unsigned* __restrict__ indices,     // [KF * npts]
    float* __restrict__ out,
    int npts, int cpx)
{
    __shared__ float sW1[INF * HID];          // 4096 B, single cluster
    __shared__ float sB1[HID];
    __shared__ float sW2[HID];
    __shared__ unsigned snk[KF];

    const int tid = threadIdx.x;
    const int b = blockIdx.x;
    const int v = (b & 7) * cpx + (b >> 3);   // chunked XCD swizzle

    if (tid < KF) snk[tid] = cursors[tid];
    __syncthreads();

    // Locate (cluster k, slot) for virtual block v in the padded-block space.
    int k = -1;
    unsigned slot = 0, nk = 0, acc = 0;
    #pragma unroll
    for (int kk = 0; kk < KF; ++kk) {
        const unsigned n = snk[kk];
        const unsigned nbk = (n + 255u) >> 8;        // padded blocks for kk
        if (k < 0 && (unsigned)v < acc + nbk) {
            k = kk; slot = (unsigned)v - acc; nk = n;
        }
        acc += nbk;
    }
    if (k < 0) return;                               // v beyond vtotal (few)

    // Single-cluster weight staging (coalesced; wave-uniform reads later).
    for (int idx = tid; idx < INF * HID; idx += blockDim.x)
        sW1[idx] = W1[k * (INF * HID) + idx];
    if (tid < HID) {
        sB1[tid] = b1[k * HID + tid];
        sW2[tid] = W2[k * HID + tid];
    }
    __syncthreads();

    const unsigned rank = slot * 256u + (unsigned)tid;
    if (rank >= nk) return;                          // tail threads only
    const unsigned pidx = indices[(size_t)k * npts + rank];

    const float px = positions[pidx * 3 + 0];
    const float py = positions[pidx * 3 + 1];
    const float pz = positions[pidx * 3 + 2];

    // ---- multiresolution hash encoding (half2 gathers, uniform table base) ----
    float enc[INF];
    const __half2* __restrict__ tab = tables + (size_t)k * (LL * (size_t)TT);

    #pragma unroll
    for (int l = 0; l < LL; ++l) {
        const float res = (float)(16 << l);
        const float sx = px * res, sy = py * res, sz = pz * res;
        const float fx = floorf(sx), fy = floorf(sy), fz = floorf(sz);
        const float wx = sx - fx, wy = sy - fy, wz = sz - fz;
        const unsigned ix = (unsigned)(int)fx;
        const unsigned iy = (unsigned)(int)fy;
        const unsigned iz = (unsigned)(int)fz;

        const __half2* __restrict__ tl = tab + (size_t)l * TT;

        const unsigned hx0 = ix;                         // prime 1
        const unsigned hx1 = ix + 1u;
        const unsigned hy0 = iy * 2654435761u;
        const unsigned hy1 = (iy + 1u) * 2654435761u;
        const unsigned hz0 = iz * 805459861u;
        const unsigned hz1 = (iz + 1u) * 805459861u;
        const unsigned M = TT - 1;

        // 8 independent 4B gathers — keep them all in flight
        const __half2 c000 = tl[(hx0 ^ hy0 ^ hz0) & M];
        const __half2 c001 = tl[(hx0 ^ hy0 ^ hz1) & M];
        const __half2 c010 = tl[(hx0 ^ hy1 ^ hz0) & M];
        const __half2 c011 = tl[(hx0 ^ hy1 ^ hz1) & M];
        const __half2 c100 = tl[(hx1 ^ hy0 ^ hz0) & M];
        const __half2 c101 = tl[(hx1 ^ hy0 ^ hz1) & M];
        const __half2 c110 = tl[(hx1 ^ hy1 ^ hz0) & M];
        const __half2 c111 = tl[(hx1 ^ hy1 ^ hz1) & M];

        const float ux = 1.f - wx, uy = 1.f - wy, uz = 1.f - wz;
        const float w000 = ux * uy * uz, w001 = ux * uy * wz;
        const float w010 = ux * wy * uz, w011 = ux * wy * wz;
        const float w100 = wx * uy * uz, w101 = wx * uy * wz;
        const float w110 = wx * wy * uz, w111 = wx * wy * wz;

        enc[l * 2 + 0] = __low2float(c000) * w000 + __low2float(c001) * w001
                       + __low2float(c010) * w010 + __low2float(c011) * w011
                       + __low2float(c100) * w100 + __low2float(c101) * w101
                       + __low2float(c110) * w110 + __low2float(c111) * w111;
        enc[l * 2 + 1] = __high2float(c000) * w000 + __high2float(c001) * w001
                       + __high2float(c010) * w010 + __high2float(c011) * w011
                       + __high2float(c100) * w100 + __high2float(c101) * w101
                       + __high2float(c110) * w110 + __high2float(c111) * w111;
    }

    // ---- MLP (single-cluster weights, wave-uniform LDS broadcasts) ----
    const float4* __restrict__ w1k = (const float4*)sW1;
    const float4* __restrict__ b1k = (const float4*)sB1;
    const float4* __restrict__ w2k = (const float4*)sW2;

    float outv = b2[k];
    #pragma unroll
    for (int j4 = 0; j4 < HID / 4; ++j4) {
        float4 a = b1k[j4];
        #pragma unroll
        for (int i = 0; i < INF; ++i) {
            const float4 w = w1k[i * (HID / 4) + j4];
            const float e = enc[i];
            a.x = fmaf(e, w.x, a.x);
            a.y = fmaf(e, w.y, a.y);
            a.z = fmaf(e, w.z, a.z);
            a.w = fmaf(e, w.w, a.w);
        }
        a.x = fmaxf(a.x, 0.f); a.y = fmaxf(a.y, 0.f);
        a.z = fmaxf(a.z, 0.f); a.w = fmaxf(a.w, 0.f);
        const float4 w2v = w2k[j4];
        outv = fmaf(a.x, w2v.x, outv);
        outv = fmaf(a.y, w2v.y, outv);
        outv = fmaf(a.z, w2v.z, outv);
        outv = fmaf(a.w, w2v.w, outv);
    }

    out[pidx] = expf(outv);
}

// ---------------- Fallback tier: unbucketed fp16 (round-5/6 kernel) ---------
__global__ __launch_bounds__(256) void propnet_density_kernel_h(
    const float* __restrict__ positions,
    const float* __restrict__ centroids,
    const __half2* __restrict__ tables,
    const float* __restrict__ W1,
    const float* __restrict__ b1,
    const float* __restrict__ W2,
    const float* __restrict__ b2,
    float* __restrict__ out,
    int npts)
{
    __shared__ float sW1[KF * W1S];
    __shared__ float sB1[KF * BS];
    __shared__ float sW2[KF * BS];
    __shared__ float sB2[KF];
    __shared__ float sC[KF * 3];

    const int tid = threadIdx.x;

    for (int idx = tid; idx < KF * INF * HID; idx += blockDim.x) {
        int k = idx >> 10;
        int r = idx & 1023;
        sW1[k * W1S + r] = W1[idx];
    }
    for (int idx = tid; idx < KF * HID; idx += blockDim.x) {
        int k = idx >> 6;
        int r = idx & 63;
        sB1[k * BS + r] = b1[idx];
        sW2[k * BS + r] = W2[idx];
    }
    if (tid < KF) sB2[tid] = b2[tid];
    if (tid < KF * 3) sC[tid] = centroids[tid];
    __syncthreads();

    const int gid = blockIdx.x * blockDim.x + tid;
    if (gid >= npts) return;

    const float px = positions[gid * 3 + 0];
    const float py = positions[gid * 3 + 1];
    const float pz = positions[gid * 3 + 2];

    int assign = argmin_cluster(sC, px, py, pz);

    float enc[INF];
    const __half2* __restrict__ tab =
        tables + (size_t)assign * (LL * (size_t)TT);

    #pragma unroll
    for (int l = 0; l < LL; ++l) {
        const float res = (float)(16 << l);
        const float sx = px * res, sy = py * res, sz = pz * res;
        const float fx = floorf(sx), fy = floorf(sy), fz = floorf(sz);
        const float wx = sx - fx, wy = sy - fy, wz = sz - fz;
        const unsigned ix = (unsigned)(int)fx;
        const unsigned iy = (unsigned)(int)fy;
        const unsigned iz = (unsigned)(int)fz;

        const __half2* __restrict__ tl = tab + (size_t)l * TT;

        const unsigned hx0 = ix;
        const unsigned hx1 = ix + 1u;
        const unsigned hy0 = iy * 2654435761u;
        const unsigned hy1 = (iy + 1u) * 2654435761u;
        const unsigned hz0 = iz * 805459861u;
        const unsigned hz1 = (iz + 1u) * 805459861u;
        const unsigned M = TT - 1;

        const __half2 c000 = tl[(hx0 ^ hy0 ^ hz0) & M];
        const __half2 c001 = tl[(hx0 ^ hy0 ^ hz1) & M];
        const __half2 c010 = tl[(hx0 ^ hy1 ^ hz0) & M];
        const __half2 c011 = tl[(hx0 ^ hy1 ^ hz1) & M];
        const __half2 c100 = tl[(hx1 ^ hy0 ^ hz0) & M];
        const __half2 c101 = tl[(hx1 ^ hy0 ^ hz1) & M];
        const __half2 c110 = tl[(hx1 ^ hy1 ^ hz0) & M];
        const __half2 c111 = tl[(hx1 ^ hy1 ^ hz1) & M];

        const float ux = 1.f - wx, uy = 1.f - wy, uz = 1.f - wz;
        const float w000 = ux * uy * uz, w001 = ux * uy * wz;
        const float w010 = ux * wy * uz, w011 = ux * wy * wz;
        const float w100 = wx * uy * uz, w101 = wx * uy * wz;
        const float w110 = wx * wy * uz, w111 = wx * wy * wz;

        enc[l * 2 + 0] = __low2float(c000) * w000 + __low2float(c001) * w001
                       + __low2float(c010) * w010 + __low2float(c011) * w011
                       + __low2float(c100) * w100 + __low2float(c101) * w101
                       + __low2float(c110) * w110 + __low2float(c111) * w111;
        enc[l * 2 + 1] = __high2float(c000) * w000 + __high2float(c001) * w001
                       + __high2float(c010) * w010 + __high2float(c011) * w011
                       + __high2float(c100) * w100 + __high2float(c101) * w101
                       + __high2float(c110) * w110 + __high2float(c111) * w111;
    }

    const float4* __restrict__ w1k = (const float4*)(sW1 + assign * W1S);
    const float4* __restrict__ b1k = (const float4*)(sB1 + assign * BS);
    const float4* __restrict__ w2k = (const float4*)(sW2 + assign * BS);

    float outv = sB2[assign];
    #pragma unroll
    for (int j4 = 0; j4 < HID / 4; ++j4) {
        float4 a = b1k[j4];
        #pragma unroll
        for (int i = 0; i < INF; ++i) {
            const float4 w = w1k[i * (HID / 4) + j4];
            const float e = enc[i];
            a.x = fmaf(e, w.x, a.x);
            a.y = fmaf(e, w.y, a.y);
            a.z = fmaf(e, w.z, a.z);
            a.w = fmaf(e, w.w, a.w);
        }
        a.x = fmaxf(a.x, 0.f); a.y = fmaxf(a.y, 0.f);
        a.z = fmaxf(a.z, 0.f); a.w = fmaxf(a.w, 0.f);
        const float4 w2v = w2k[j4];
        outv = fmaf(a.x, w2v.x, outv);
        outv = fmaf(a.y, w2v.y, outv);
        outv = fmaf(a.z, w2v.z, outv);
        outv = fmaf(a.w, w2v.w, outv);
    }

    out[gid] = expf(outv);
}

// ---------------- Fallback tier: fp32 (round-0 kernel) ----------------------
__global__ __launch_bounds__(256) void propnet_density_kernel_f(
    const float* __restrict__ positions,
    const float* __restrict__ centroids,
    const float* __restrict__ tables,
    const float* __restrict__ W1,
    const float* __restrict__ b1,
    const float* __restrict__ W2,
    const float* __restrict__ b2,
    float* __restrict__ out,
    int npts)
{
    __shared__ float sW1[KF * W1S];
    __shared__ float sB1[KF * BS];
    __shared__ float sW2[KF * BS];
    __shared__ float sB2[KF];
    __shared__ float sC[KF * 3];

    const int tid = threadIdx.x;

    for (int idx = tid; idx < KF * INF * HID; idx += blockDim.x) {
        int k = idx >> 10;
        int r = idx & 1023;
        sW1[k * W1S + r] = W1[idx];
    }
    for (int idx = tid; idx < KF * HID; idx += blockDim.x) {
        int k = idx >> 6;
        int r = idx & 63;
        sB1[k * BS + r] = b1[idx];
        sW2[k * BS + r] = W2[idx];
    }
    if (tid < KF) sB2[tid] = b2[tid];
    if (tid < KF * 3) sC[tid] = centroids[tid];
    __syncthreads();

    const int gid = blockIdx.x * blockDim.x + tid;
    if (gid >= npts) return;

    const float px = positions[gid * 3 + 0];
    const float py = positions[gid * 3 + 1];
    const float pz = positions[gid * 3 + 2];

    int assign = argmin_cluster(sC, px, py, pz);

    float enc[INF];
    const float2* __restrict__ tab =
        (const float2*)tables + (size_t)assign * (LL * (size_t)TT);

    #pragma unroll
    for (int l = 0; l < LL; ++l) {
        const float res = (float)(16 << l);
        const float sx = px * res, sy = py * res, sz = pz * res;
        const float fx = floorf(sx), fy = floorf(sy), fz = floorf(sz);
        const float wx = sx - fx, wy = sy - fy, wz = sz - fz;
        const unsigned ix = (unsigned)(int)fx;
        const unsigned iy = (unsigned)(int)fy;
        const unsigned iz = (unsigned)(int)fz;

        const float2* __restrict__ tl = tab + (size_t)l * TT;

        const unsigned hx0 = ix;
        const unsigned hx1 = ix + 1u;
        const unsigned hy0 = iy * 2654435761u;
        const unsigned hy1 = (iy + 1u) * 2654435761u;
        const unsigned hz0 = iz * 805459861u;
        const unsigned hz1 = (iz + 1u) * 805459861u;
        const unsigned M = TT - 1;

        const float2 c000 = tl[(hx0 ^ hy0 ^ hz0) & M];
        const float2 c001 = tl[(hx0 ^ hy0 ^ hz1) & M];
        const float2 c010 = tl[(hx0 ^ hy1 ^ hz0) & M];
        const float2 c011 = tl[(hx0 ^ hy1 ^ hz1) & M];
        const float2 c100 = tl[(hx1 ^ hy0 ^ hz0) & M];
        const float2 c101 = tl[(hx1 ^ hy0 ^ hz1) & M];
        const float2 c110 = tl[(hx1 ^ hy1 ^ hz0) & M];
        const float2 c111 = tl[(hx1 ^ hy1 ^ hz1) & M];

        const float ux = 1.f - wx, uy = 1.f - wy, uz = 1.f - wz;
        const float w000 = ux * uy * uz, w001 = ux * uy * wz;
        const float w010 = ux * wy * uz, w011 = ux * wy * wz;
        const float w100 = wx * uy * uz, w101 = wx * uy * wz;
        const float w110 = wx * wy * uz, w111 = wx * wy * wz;

        enc[l * 2 + 0] = c000.x * w000 + c001.x * w001 + c010.x * w010 + c011.x * w011
                       + c100.x * w100 + c101.x * w101 + c110.x * w110 + c111.x * w111;
        enc[l * 2 + 1] = c000.y * w000 + c001.y * w001 + c010.y * w010 + c011.y * w011
                       + c100.y * w100 + c101.y * w101 + c110.y * w110 + c111.y * w111;
    }

    const float4* __restrict__ w1k = (const float4*)(sW1 + assign * W1S);
    const float4* __restrict__ b1k = (const float4*)(sB1 + assign * BS);
    const float4* __restrict__ w2k = (const float4*)(sW2 + assign * BS);

    float outv = sB2[assign];
    #pragma unroll
    for (int j4 = 0; j4 < HID / 4; ++j4) {
        float4 a = b1k[j4];
        #pragma unroll
        for (int i = 0; i < INF; ++i) {
            const float4 w = w1k[i * (HID / 4) + j4];
            const float e = enc[i];
            a.x = fmaf(e, w.x, a.x);
            a.y = fmaf(e, w.y, a.y);
            a.z = fmaf(e, w.z, a.z);
            a.w = fmaf(e, w.w, a.w);
        }
        a.x = fmaxf(a.x, 0.f); a.y = fmaxf(a.y, 0.f);
        a.z = fmaxf(a.z, 0.f); a.w = fmaxf(a.w, 0.f);
        const float4 w2v = w2k[j4];
        outv = fmaf(a.x, w2v.x, outv);
        outv = fmaf(a.y, w2v.y, outv);
        outv = fmaf(a.z, w2v.z, outv);
        outv = fmaf(a.w, w2v.w, outv);
    }

    out[gid] = expf(outv);
}

extern "C" void kernel_launch(void* const* d_in, const int* in_sizes, int n_in,
                              void* d_out, int out_size, void* d_ws, size_t ws_size,
                              hipStream_t stream) {
    const float* positions = (const float*)d_in[0];
    const float* centroids = (const float*)d_in[1];
    const float* tables    = (const float*)d_in[2];
    const float* W1        = (const float*)d_in[3];
    const float* b1        = (const float*)d_in[4];
    const float* W2        = (const float*)d_in[5];
    const float* b2        = (const float*)d_in[6];
    float* out = (float*)d_out;

    const int npts = in_sizes[0] / 3;
    const int block = 256;
    const int nb = (npts + block - 1) / block;

    const size_t idx_bytes   = (size_t)KF * npts * 4;
    const size_t need_h      = TAB_BYTES;                              // 64 Mi
    const size_t need_bucket = TAB_BYTES + 256 + idx_bytes;            // ~80 Mi
    const size_t need_sorted = need_bucket + (size_t)NKEY * 4
                             + (size_t)npts * 4;                       // +2.1 Mi

    if (ws_size >= need_bucket && d_ws != nullptr) {
        char* base = (char*)d_ws;
        __half2*  wsTab   = (__half2*)base;
        unsigned* cursors = (unsigned*)(base + TAB_BYTES);   // 16 u32 used
        unsigned* indices = (unsigned*)(base + TAB_BYTES + 256);

        const int rthreads = NENT / 8;
        repack_tables_fp16<<<rthreads / 256, 256, 0, stream>>>(
            (const float4*)tables, (uint4*)wsTab, rthreads);

        if (ws_size >= need_sorted) {
            unsigned* hist   = (unsigned*)(base + TAB_BYTES + 256 + idx_bytes);
            unsigned* packed = hist + NKEY;
            hipMemsetAsync(hist, 0, (size_t)NKEY * 4, stream);
            assign_rank<<<nb, block, 0, stream>>>(
                positions, centroids, hist, packed, npts);
            scan_hist<<<1, 1024, 0, stream>>>(hist, cursors, npts);
            place_sorted<<<nb, block, 0, stream>>>(
                packed, hist, cursors, indices, npts);
        } else {
            zero_cursors<<<1, 64, 0, stream>>>(cursors);
            bucket_points<<<nb, block, 0, stream>>>(
                positions, centroids, cursors, indices, npts);
        }

        const int G = ((nb + KF + 7) / 8) * 8;
        const int cpx = G / 8;
        propnet_density_balanced<<<G, block, 0, stream>>>(
            positions, wsTab, W1, b1, W2, b2, cursors, indices, out, npts, cpx);
    } else if (ws_size >= need_h && d_ws != nullptr) {
        const int rthreads = NENT / 8;
        repack_tables_fp16<<<rthreads / 256, 256, 0, stream>>>(
            (const float4*)tables, (uint4*)d_ws, rthreads);
        propnet_density_kernel_h<<<nb, block, 0, stream>>>(
            positions, centroids, (const __half2*)d_ws, W1, b1, W2, b2, out, npts);
    } else {
        propnet_density_kernel_f<<<nb, block, 0, stream>>>(
            positions, centroids, tables, W1, b1, W2, b2, out, npts);
    }
}